// Round 9
// baseline (101.720 us; speedup 1.0000x reference)
//
#include <hip/hip_runtime.h>
#include <stdint.h>

using u16 = unsigned short;
using u32 = unsigned int;
using bf16x8 = __bf16 __attribute__((ext_vector_type(8)));
using f32x4  = float __attribute__((ext_vector_type(4)));

__device__ __forceinline__ float bflo(u32 u){ return __uint_as_float(u << 16); }
__device__ __forceinline__ float bfhi(u32 u){ return __uint_as_float(u & 0xffff0000u); }
__device__ __forceinline__ u16 f2bf(float f){
  u32 u = __float_as_uint(f);
  u += 0x7fffu + ((u >> 16) & 1u);
  return (u16)(u >> 16);
}
__device__ __forceinline__ u32 pk2(float a, float b){
  return (u32)f2bf(a) | ((u32)f2bf(b) << 16);
}
__device__ __forceinline__ void gload16(const void* g, void* l){
  __builtin_amdgcn_global_load_lds(
      (const __attribute__((address_space(1))) void*)(uintptr_t)(g),
      (__attribute__((address_space(3))) void*)(uintptr_t)(l), 16, 0, 0);
}

// ---------------- fused LayerNorm cast (blocks < 12288) + weight transpose ----------------
__global__ __launch_bounds__(256) void prepcast_k(
    const float* __restrict__ q, const float* __restrict__ k, const float* __restrict__ v,
    const float* __restrict__ lnw, const float* __restrict__ lnb,
    u16* __restrict__ xnq, u16* __restrict__ xnk, u16* __restrict__ xnv,
    const float* __restrict__ Win, const float* __restrict__ Wout,
    u16* __restrict__ WinT, u16* __restrict__ WoutT){
  __shared__ float tile[32][33];
  if (blockIdx.x >= 12288){
    int bi = blockIdx.x - 12288;           // 0..511
    int bz = bi >> 8; bi &= 255;
    int bx = bi & 15, by = bi >> 4;
    const float* src = bz ? Wout : Win;
    u16* dst = bz ? WoutT : WinT;
    int tx = threadIdx.x & 31, ty = threadIdx.x >> 5;
    int c0 = bx * 32, r0 = by * 32;
#pragma unroll
    for (int i = 0; i < 4; ++i)
      tile[ty + i*8][tx] = src[(size_t)(r0 + ty + i*8)*512 + c0 + tx];
    __syncthreads();
#pragma unroll
    for (int i = 0; i < 4; ++i)
      dst[(size_t)(c0 + ty + i*8)*512 + r0 + tx] = f2bf(tile[tx][ty + i*8]);
    return;
  }
  int row = blockIdx.x * 4 + (threadIdx.x >> 6);
  int l = threadIdx.x & 63;
  const float* x = (row < 16384) ? q : (row < 32768) ? k : v;
  u16* xo = (row < 16384) ? xnq : (row < 32768) ? xnk : xnv;
  int r = row & 16383;
  const float* rp = x + (size_t)r * 512 + l*8;
  float4 a = *(const float4*)rp, c = *(const float4*)(rp + 4);
  float sum = ((a.x+a.y)+(a.z+a.w)) + ((c.x+c.y)+(c.z+c.w));
  float ss  = ((a.x*a.x+a.y*a.y)+(a.z*a.z+a.w*a.w)) + ((c.x*c.x+c.y*c.y)+(c.z*c.z+c.w*c.w));
#pragma unroll
  for (int off = 32; off; off >>= 1){
    sum += __shfl_xor(sum, off);
    ss  += __shfl_xor(ss,  off);
  }
  float mu = sum * (1.f/512.f);
  float rs = rsqrtf(ss * (1.f/512.f) - mu*mu + 1e-5f);
  float4 w0 = *(const float4*)(lnw + l*8), w1 = *(const float4*)(lnw + l*8 + 4);
  float4 b0 = *(const float4*)(lnb + l*8), b1 = *(const float4*)(lnb + l*8 + 4);
  uint4 pk;
  pk.x = pk2((a.x-mu)*rs*w0.x + b0.x, (a.y-mu)*rs*w0.y + b0.y);
  pk.y = pk2((a.z-mu)*rs*w0.z + b0.z, (a.w-mu)*rs*w0.w + b0.w);
  pk.z = pk2((c.x-mu)*rs*w1.x + b1.x, (c.y-mu)*rs*w1.y + b1.y);
  pk.w = pk2((c.z-mu)*rs*w1.z + b1.z, (c.w-mu)*rs*w1.w + b1.w);
  *(uint4*)((char*)xo + (size_t)r*1024 + l*16) = pk;
}

// ---------------- pure bf16 GEMM body: C[r][c] = sum_k A[r][k]*B[c][k] ----------------
// Serial 2-barrier loop, both operands via global_load_lds (DMA, no in-loop VALU).
// MAP 0: bx=bid&127, by=bid>>7 (token-row tiles; +128 siblings share XCD)
// MAP 1: j=bid>>3; bx=j&3; by=(bid&7)+8*(j>>2) (token-panel siblings share XCD)
// FSTAT: 0 none, 1 per-row-per-head (sum,ss), 2 per-col-per-head (sum,ss)
template<int MAP, int FSTAT>
__device__ __forceinline__ void gemm_body(
    const u16* __restrict__ A, const u16* __restrict__ B,
    u16* __restrict__ C, float* __restrict__ stat, int ldC, int bid,
    char* sA, char* sB){
  const int t = threadIdx.x, w = t >> 6, l = t & 63;
  const int wr = w >> 1, wc = w & 1;
  const int lr = l & 15, lg = l >> 4;
  int bx, by;
  if (MAP == 0){ bx = bid & 127; by = bid >> 7; }
  else { int j = bid >> 3; bx = j & 3; by = (bid & 7) + 8*(j >> 2); }
  const int row0 = bx * 128, col0 = by * 128;
  f32x4 acc[4][4] = {};

  const int sc = t >> 3, k8 = t & 7;
  const int sso = (k8*16) ^ ((sc & 7) << 4);
  const char* Ap = (const char*)A + ((size_t)(row0 + sc) << 10) + sso;
  const char* Bp = (const char*)B + ((size_t)(col0 + sc) << 10) + sso;

  for (int kt = 0; kt < 8; ++kt){
    __syncthreads();
#pragma unroll
    for (int ii = 0; ii < 4; ++ii){
      gload16(Ap + (size_t)ii*32768 + kt*128, sA + ii*4096 + w*1024);
      gload16(Bp + (size_t)ii*32768 + kt*128, sB + ii*4096 + w*1024);
    }
    __syncthreads();
#pragma unroll
    for (int kk = 0; kk < 2; ++kk){
      bf16x8 af[4], bfg[4];
#pragma unroll
      for (int m = 0; m < 4; ++m){
        int r = wr*64 + m*16 + lr;
        af[m] = *(const bf16x8*)(sA + r*128 + ((kk*64 + lg*16) ^ ((r & 7) << 4)));
      }
#pragma unroll
      for (int n = 0; n < 4; ++n){
        int r = wc*64 + n*16 + lr;
        bfg[n] = *(const bf16x8*)(sB + r*128 + ((kk*64 + lg*16) ^ ((r & 7) << 4)));
      }
#pragma unroll
      for (int m = 0; m < 4; ++m)
#pragma unroll
        for (int n = 0; n < 4; ++n)
          acc[m][n] = __builtin_amdgcn_mfma_f32_16x16x32_bf16(af[m], bfg[n], acc[m][n], 0, 0, 0);
    }
  }
  // epilogue: D row-in-tile = lg*4+q, col-in-tile = lr
  float cs[4] = {}, cs2[4] = {};
#pragma unroll
  for (int m = 0; m < 4; ++m){
#pragma unroll
    for (int q = 0; q < 4; ++q){
      int ri = wr*64 + m*16 + lg*4 + q;
      float fv[4];
#pragma unroll
      for (int n = 0; n < 4; ++n){
        int ci = wc*64 + n*16 + lr;
        fv[n] = acc[m][n][q];
        C[(size_t)(row0 + ri)*ldC + (col0 + ci)] = f2bf(fv[n]);
        if (FSTAT == 2){ cs[n] += fv[n]; cs2[n] += fv[n]*fv[n]; }
      }
      if (FSTAT == 1){
        float s  = (fv[0]+fv[1]) + (fv[2]+fv[3]);
        float s2 = (fv[0]*fv[0]+fv[1]*fv[1]) + (fv[2]*fv[2]+fv[3]*fv[3]);
#pragma unroll
        for (int off = 1; off < 16; off <<= 1){ s += __shfl_xor(s, off); s2 += __shfl_xor(s2, off); }
        if (lr == 0){
          int head = (col0 >> 6) + wc;
          *(float2*)(stat + ((size_t)(row0 + ri)*8 + head)*2) = make_float2(s, s2);
        }
      }
    }
  }
  if (FSTAT == 2){
    int head = (row0 >> 6) + wr;
#pragma unroll
    for (int n = 0; n < 4; ++n){
      float s = cs[n], s2 = cs2[n];
      s += __shfl_xor(s, 16); s2 += __shfl_xor(s2, 16);
      s += __shfl_xor(s, 32); s2 += __shfl_xor(s2, 32);
      if (lg == 0){
        int tok = col0 + wc*64 + n*16 + lr;
        *(float2*)(stat + ((size_t)tok*8 + head)*2) = make_float2(s, s2);
      }
    }
  }
}

// ---------------- merged Q/K/V projection: 1536 blocks ----------------
__global__ __launch_bounds__(256) void proj_k(
    const u16* __restrict__ xnq, const u16* __restrict__ xnk, const u16* __restrict__ xnv,
    const u16* __restrict__ Wt,
    u16* __restrict__ fq, u16* __restrict__ kT, u16* __restrict__ vT,
    float* __restrict__ qstat, float* __restrict__ kstat){
  __shared__ __align__(16) char sA[16384];
  __shared__ __align__(16) char sB[16384];
  int bid = blockIdx.x;
  if (bid < 512)
    gemm_body<0,1>(xnq, Wt, fq, qstat, 512, bid, sA, sB);
  else if (bid < 1024)
    gemm_body<1,2>(Wt, xnk, kT, kstat, 16384, bid - 512, sA, sB);
  else
    gemm_body<1,0>(Wt, xnv, vT, nullptr, 16384, bid - 1024, sA, sB);
}

// ---------------- out GEMM: C = ao @ WoutT^T + bias (f32) ----------------
__global__ __launch_bounds__(256) void outgemm_k(
    const u16* __restrict__ A, const u16* __restrict__ B,
    float* __restrict__ Cf, const float* __restrict__ bias){
  __shared__ __align__(16) char sA[16384];
  __shared__ __align__(16) char sB[16384];
  const int t = threadIdx.x, w = t >> 6, l = t & 63;
  const int wr = w >> 1, wc = w & 1;
  const int lr = l & 15, lg = l >> 4;
  const int row0 = blockIdx.x * 128, col0 = blockIdx.y * 128;
  f32x4 acc[4][4] = {};

  const int sc = t >> 3, k8 = t & 7;
  const int sso = (k8*16) ^ ((sc & 7) << 4);
  const char* Ap = (const char*)A + ((size_t)(row0 + sc) << 10) + sso;
  const char* Bp = (const char*)B + ((size_t)(col0 + sc) << 10) + sso;

  for (int kt = 0; kt < 8; ++kt){
    __syncthreads();
#pragma unroll
    for (int ii = 0; ii < 4; ++ii){
      gload16(Ap + (size_t)ii*32768 + kt*128, sA + ii*4096 + w*1024);
      gload16(Bp + (size_t)ii*32768 + kt*128, sB + ii*4096 + w*1024);
    }
    __syncthreads();
#pragma unroll
    for (int kk = 0; kk < 2; ++kk){
      bf16x8 af[4], bfg[4];
#pragma unroll
      for (int m = 0; m < 4; ++m){
        int r = wr*64 + m*16 + lr;
        af[m] = *(const bf16x8*)(sA + r*128 + ((kk*64 + lg*16) ^ ((r & 7) << 4)));
      }
#pragma unroll
      for (int n = 0; n < 4; ++n){
        int r = wc*64 + n*16 + lr;
        bfg[n] = *(const bf16x8*)(sB + r*128 + ((kk*64 + lg*16) ^ ((r & 7) << 4)));
      }
#pragma unroll
      for (int m = 0; m < 4; ++m)
#pragma unroll
        for (int n = 0; n < 4; ++n)
          acc[m][n] = __builtin_amdgcn_mfma_f32_16x16x32_bf16(af[m], bfg[n], acc[m][n], 0, 0, 0);
    }
  }
#pragma unroll
  for (int m = 0; m < 4; ++m){
#pragma unroll
    for (int q = 0; q < 4; ++q){
      int r = row0 + wr*64 + m*16 + lg*4 + q;
#pragma unroll
      for (int n = 0; n < 4; ++n){
        int cc = col0 + wc*64 + n*16 + lr;
        Cf[(size_t)r*512 + cc] = acc[m][n][q] + bias[cc];
      }
    }
  }
}

// ---------------- attention: per (h,b), factored rank-64 form, MFMA ----------------
__global__ __launch_bounds__(512) void attn_k(
    const u16* __restrict__ fq, const u16* __restrict__ kT, const u16* __restrict__ vT,
    const float* __restrict__ qstat, const float* __restrict__ kstat,
    u16* __restrict__ ao,
    const float* __restrict__ cwr, const float* __restrict__ vwr){
  __shared__ __align__(16) char smem[131072 + 1664*4];
  float* sStat = (float*)(smem + 131072);
  float* sS1 = sStat + 1536;
  float* sS2 = sStat + 1600;

  const int t = threadIdx.x, w = t >> 6, l = t & 63;
  const int lr = l & 15, lg = l >> 4;
  const int h = blockIdx.x & 7, b = blockIdx.x >> 3;

  float cwv = 1.f/(1.f + __expf(-*cwr));
  float vwv = 1.f/(1.f + __expf(-*vwr));
  float cosw = 1.f - cwv - vwv;

  const char* kTb = (const char*)kT + (size_t)h*64*32768 + (size_t)b*1024;
  const char* vTb = (const char*)vT + (size_t)h*64*32768 + (size_t)b*1024;
#pragma unroll
  for (int ii = 0; ii < 8; ++ii){
    int c = ii*512 + t, d = c >> 6, u = c & 63;
    int so = d*32768 + ((u ^ (d & 7)) << 4);
    gload16(kTb + so, smem + ii*8192 + w*1024);
    gload16(vTb + so, smem + 65536 + ii*8192 + w*1024);
  }
  {
    float2 ksr = *(const float2*)(kstat + ((size_t)(b*512 + t)*8 + h)*2);
    float mk = ksr.x * (1.f/64.f);
    sStat[t]        = rsqrtf(ksr.y);
    sStat[512 + t]  = mk;
    sStat[1024 + t] = (ksr.y - 64.f*mk*mk) * (1.f/63.f);
  }
  __syncthreads();

  const int jt = (w >> 1), itp = (w & 1);
  f32x4 m2acc[2] = {}, m1acc[2] = {};
  {
    const int j = jt*16 + lr;
#pragma unroll
    for (int ks = 0; ks < 16; ++ks){
      int u = ks*4 + lg;
      bf16x8 af = *(const bf16x8*)(smem + 65536 + j*1024 + ((u ^ (j & 7)) << 4));
#pragma unroll
      for (int tt = 0; tt < 2; ++tt){
        int i = (itp*2 + tt)*16 + lr;
        bf16x8 bf = *(const bf16x8*)(smem + i*1024 + ((u ^ (i & 7)) << 4));
        m2acc[tt] = __builtin_amdgcn_mfma_f32_16x16x32_bf16(af, bf, m2acc[tt], 0, 0, 0);
      }
    }
  }
  {
    int j = t >> 3, g = t & 7;
    float p1 = 0.f, p2 = 0.f;
#pragma unroll
    for (int uu = 0; uu < 8; ++uu){
      int ut = g*8 + uu;
      uint4 uv = *(const uint4*)(smem + 65536 + j*1024 + ((ut ^ (j & 7)) << 4));
      int m0 = ut*8;
      float4 mk0 = *(const float4*)(sStat + 512 + m0);
      float4 mk1 = *(const float4*)(sStat + 512 + m0 + 4);
      float4 kv0 = *(const float4*)(sStat + 1024 + m0);
      float4 kv1 = *(const float4*)(sStat + 1024 + m0 + 4);
      float v0=bflo(uv.x),v1=bfhi(uv.x),v2=bflo(uv.y),v3=bfhi(uv.y);
      float v4=bflo(uv.z),v5=bfhi(uv.z),v6=bflo(uv.w),v7=bfhi(uv.w);
      p1 += v0*mk0.x + v1*mk0.y + v2*mk0.z + v3*mk0.w
          + v4*mk1.x + v5*mk1.y + v6*mk1.z + v7*mk1.w;
      p2 += v0*kv0.x + v1*kv0.y + v2*kv0.z + v3*kv0.w
          + v4*kv1.x + v5*kv1.y + v6*kv1.z + v7*kv1.w;
    }
#pragma unroll
    for (int off = 1; off < 8; off <<= 1){ p1 += __shfl_xor(p1, off); p2 += __shfl_xor(p2, off); }
    if (g == 0){ sS1[j] = p1; sS2[j] = p2; }
  }
  __syncthreads();

#pragma unroll
  for (int ii = 0; ii < 32; ++ii){
    int wd = ii*512 + t;
    int d = wd >> 8, o = wd & 255, ud = o >> 2, p = o & 3;
    int m0 = ((ud ^ (d & 7)) << 3) + p*2;
    u32 uv = *(u32*)(smem + wd*4);
    *(u32*)(smem + wd*4) = pk2(bflo(uv)*sStat[m0], bfhi(uv)*sStat[m0+1]);
  }
  __syncthreads();

  {
    const int j = jt*16 + lr;
#pragma unroll
    for (int ks = 0; ks < 16; ++ks){
      int u = ks*4 + lg;
      bf16x8 af = *(const bf16x8*)(smem + 65536 + j*1024 + ((u ^ (j & 7)) << 4));
#pragma unroll
      for (int tt = 0; tt < 2; ++tt){
        int i = (itp*2 + tt)*16 + lr;
        bf16x8 bf = *(const bf16x8*)(smem + i*1024 + ((u ^ (i & 7)) << 4));
        m1acc[tt] = __builtin_amdgcn_mfma_f32_16x16x32_bf16(af, bf, m1acc[tt], 0, 0, 0);
      }
    }
  }
  __syncthreads();

#pragma unroll
  for (int tt = 0; tt < 2; ++tt){
#pragma unroll
    for (int q = 0; q < 4; ++q){
      int j = jt*16 + lg*4 + q;
      int i = (itp*2 + tt)*16 + lr;
      int bo = j*128 + (((i >> 3) ^ (j & 7)) << 4) + (i & 7)*2;
      *(u16*)(smem + bo)        = f2bf(m1acc[tt][q]);
      *(u16*)(smem + 8192 + bo) = f2bf(m2acc[tt][q]);
    }
  }
  const char* fqb = (const char*)fq + (size_t)b*524288 + h*128;
#pragma unroll
  for (int ii = 0; ii < 8; ++ii){
    int c = ii*512 + t, n = c >> 3, u = c & 7;
    gload16(fqb + n*1024 + ((u ^ (n & 7)) << 4), smem + 65536 + ii*8192 + w*1024);
  }
  __syncthreads();

  float s1v[4], s2v[4];
#pragma unroll
  for (int nt = 0; nt < 4; ++nt){ s1v[nt] = sS1[nt*16 + lr]; s2v[nt] = sS2[nt*16 + lr]; }
  const float Bc = cwv * (1.f/64.f);

#pragma unroll
  for (int mt = 0; mt < 4; ++mt){
    f32x4 a1[4] = {}, a2[4] = {};
    const int n = w*64 + mt*16 + lr;
#pragma unroll
    for (int kk = 0; kk < 2; ++kk){
      int u = kk*4 + lg;
      bf16x8 af = *(const bf16x8*)(smem + 65536 + n*128 + ((u ^ (n & 7)) << 4));
#pragma unroll
      for (int nt = 0; nt < 4; ++nt){
        int j = nt*16 + lr;
        bf16x8 b1 = *(const bf16x8*)(smem + j*128 + ((u ^ (j & 7)) << 4));
        bf16x8 b2 = *(const bf16x8*)(smem + 8192 + j*128 + ((u ^ (j & 7)) << 4));
        a1[nt] = __builtin_amdgcn_mfma_f32_16x16x32_bf16(af, b1, a1[nt], 0, 0, 0);
        a2[nt] = __builtin_amdgcn_mfma_f32_16x16x32_bf16(af, b2, a2[nt], 0, 0, 0);
      }
    }
#pragma unroll
    for (int q = 0; q < 4; ++q){
      int nr = w*64 + mt*16 + lg*4 + q;
      float2 qs = *(const float2*)(qstat + ((size_t)(b*512 + nr)*8 + h)*2);
      float mq = qs.x * (1.f/64.f);
      float An = cosw * rsqrtf(qs.y);
      float Cn = -cwv * mq;
      float En = vwv * (1.f/64.f) * ((qs.y - 64.f*mq*mq) * (1.f/63.f));
      char* op = (char*)ao + ((size_t)(b*512 + nr)*512 + h*64)*2;
#pragma unroll
      for (int nt = 0; nt < 4; ++nt){
        float ov = An*a1[nt][q] + Bc*a2[nt][q] + Cn*s1v[nt] + En*s2v[nt];
        *(u16*)(op + (nt*16 + lr)*2) = f2bf(ov);
      }
    }
  }
}

// ---------------- launch ----------------
extern "C" void kernel_launch(void* const* d_in, const int* in_sizes, int n_in,
                              void* d_out, int out_size, void* d_ws, size_t ws_size,
                              hipStream_t stream){
  const float* q    = (const float*)d_in[0];
  const float* k    = (const float*)d_in[1];
  const float* v    = (const float*)d_in[2];
  const float* lnw  = (const float*)d_in[3];
  const float* lnb  = (const float*)d_in[4];
  const float* Win  = (const float*)d_in[5];
  const float* Wout = (const float*)d_in[6];
  const float* bout = (const float*)d_in[7];
  const float* cwr  = (const float*)d_in[8];
  const float* vwr  = (const float*)d_in[9];

  char* ws = (char*)d_ws;
  const size_t FB = (size_t)16384 * 512 * 2;   // 16 MiB bf16 buffer
  u16* xnq = (u16*)(ws);
  u16* xnk = (u16*)(ws + FB);
  u16* xnv = (u16*)(ws + 2*FB);
  u16* fq  = (u16*)(ws + 3*FB);
  u16* kT  = (u16*)(ws + 4*FB);
  u16* vT  = (u16*)(ws + 5*FB);
  u16* ao  = (u16*)(ws + 6*FB);
  u16* WinT  = (u16*)(ws + 7*FB);
  u16* WoutT = (u16*)(ws + 7*FB + 524288);
  float* qstat = (float*)d_out;            // scratch in d_out (dead before out-GEMM)
  float* kstat = qstat + 262144;

  // LN+cast q/k/v -> bf16 xn, plus plain weight transposes
  prepcast_k<<<12800, 256, 0, stream>>>(q, k, v, lnw, lnb, xnq, xnk, xnv,
                                        Win, Wout, WinT, WoutT);

  // merged pure-bf16 projections: [0,512) Q->fq(+qstat), [512,1024) K->kT(+kstat), [1024,1536) V->vT
  proj_k<<<1536, 256, 0, stream>>>(xnq, xnk, xnv, WinT, fq, kT, vT, qstat, kstat);

  attn_k<<<256, 512, 0, stream>>>(fq, kT, vT, qstat, kstat, ao, cwr, vwr);

  outgemm_k<<<dim3(128,4), 256, 0, stream>>>(ao, WoutT, (float*)d_out, bout);
}